// Round 1
// baseline (36.866 us; speedup 1.0000x reference)
//
#include <hip/hip_runtime.h>

#define OUT_H 7
#define OUT_W 7
#define NCH   256
#define FH    64
#define FW    64
#define MAXR  34   // max region span: ceil(523/16)+1 = 34

__global__ __launch_bounds__(64) void roipool_kernel(
    const float* __restrict__ fm,   // (B, C, H, W)
    const int*   __restrict__ rois, // (N, 5): b, x1, y1, x2, y2
    float*       __restrict__ out)  // (N, C, 7, 7)
{
    const int blk = blockIdx.x;     // n*NCH + c
    const int n   = blk >> 8;
    const int c   = blk & 255;
    const int tid = threadIdx.x;

    const int* r = rois + n * 5;
    const int b   = r[0];
    const int ltx = r[1] >> 4;      // exact: x * (1/16.f) truncated, x < 1024
    const int lty = r[2] >> 4;
    const int rbx = r[3] >> 4;
    const int rby = r[4] >> 4;

    int h_roi = rby - lty + 1;
    int w_roi = rbx - ltx + 1;
    if (h_roi > MAXR) h_roi = MAXR; // cannot trigger; LDS safety
    if (w_roi > MAXR) w_roi = MAXR;

    __shared__ float lds[MAXR][MAXR + 1];

    // Stage region rows coalesced: w_roi (<=34) lanes active per row.
    const float* src = fm + ((size_t)(b * NCH + c) * FH + lty) * FW + ltx;
    if (tid < w_roi) {
        for (int hh = 0; hh < h_roi; ++hh) {
            lds[hh][tid] = src[hh * FW + tid];
        }
    }
    __syncthreads();

    if (tid < OUT_H * OUT_W) {
        const int i = tid / OUT_W;       // compile-time divisor
        const int j = tid - i * OUT_W;

        const int hs = (i * h_roi) / OUT_H;
        const int he = ((i + 1) * h_roi + OUT_H - 1) / OUT_H;  // ceil
        const int ws = (j * w_roi) / OUT_W;
        const int we = ((j + 1) * w_roi + OUT_W - 1) / OUT_W;

        float m = -INFINITY;
        for (int hh = hs; hh < he; ++hh)
            for (int ww = ws; ww < we; ++ww)
                m = fmaxf(m, lds[hh][ww]);

        out[(size_t)blk * (OUT_H * OUT_W) + tid] = m;
    }
}

extern "C" void kernel_launch(void* const* d_in, const int* in_sizes, int n_in,
                              void* d_out, int out_size, void* d_ws, size_t ws_size,
                              hipStream_t stream) {
    const float* fm   = (const float*)d_in[0];
    const int*   rois = (const int*)d_in[1];
    float*       out  = (float*)d_out;

    const int N = in_sizes[1] / 5;       // 256 rois
    dim3 grid(N * NCH);                  // 65536 blocks
    dim3 block(64);
    roipool_kernel<<<grid, block, 0, stream>>>(fm, rois, out);
}

// Round 2
// 36.302 us; speedup vs baseline: 1.0155x; 1.0155x over previous
//
#include <hip/hip_runtime.h>

#define OUT_H 7
#define OUT_W 7
#define NCH   256
#define FH    64
#define FW    64
#define MAXH  34   // max region rows: ceil(523/16)+1
#define QMAX  10   // max 16B quads per region row (34 span + align slop)
#define LDSW  40   // floats per LDS row = QMAX*4 (mult of 4 for b128 stores)
#define WPB   4    // independent waves per block

__global__ __launch_bounds__(256) void roipool_kernel(
    const float* __restrict__ fm,   // (B, C, H, W)
    const int*   __restrict__ rois, // (N, 5): b, x1, y1, x2, y2
    float*       __restrict__ out)  // (N, C, 7, 7)
{
    __shared__ __align__(16) float lds[WPB][MAXH][LDSW];  // 21760 B

    const int tid  = threadIdx.x;
    const int wv   = tid >> 6;
    const int lane = tid & 63;
    const int task = blockIdx.x * WPB + wv;   // n*NCH + c
    const int n    = task >> 8;
    const int c    = task & 255;

    const int* r = rois + n * 5;
    const int b   = r[0];
    const int ltx = r[1] >> 4;     // exact: x*(1/16.f) trunc, 0<=x<1024
    const int lty = r[2] >> 4;
    const int rbx = r[3] >> 4;
    const int rby = r[4] >> 4;

    const int h_roi = rby - lty + 1;           // 1..34, always >=1
    const int w_roi = rbx - ltx + 1;
    const int qs    = ltx >> 2;                // first aligned quad
    const int qn    = (rbx >> 2) - qs + 1;     // quads to stage (<=10)
    const int off   = ltx & 3;                 // LDS col offset of ltx

    // ---- stage: lane -> (row rr, quad qq); 6 rows x 10 quads per pass ----
    const float4* srcq =
        (const float4*)(fm + ((size_t)(b * NCH + c) * FH + lty) * FW) + qs;
    const int rr = lane / 10;        // 0..6 (lanes 60..63 duplicate row work)
    const int qq = lane - rr * 10;   // 0..9
    if (qq < qn) {
        for (int hh = rr; hh < h_roi; hh += 6) {
            float4 v = srcq[hh * (FW / 4) + qq];
            ((float4*)&lds[wv][hh][0])[qq] = v;   // dup writes (lanes>=60) benign
        }
    }
    // no barrier: same wave produces and consumes; lgkmcnt orders DS ops

    // ---- compute: lane = i*7+j output cell ----
    if (lane < OUT_H * OUT_W) {
        const int i = lane / OUT_W;
        const int j = lane - i * OUT_W;

        const int hs = (i * h_roi) / OUT_H;
        const int he = ((i + 1) * h_roi + OUT_H - 1) / OUT_H;
        const int ws = (j * w_roi) / OUT_W + off;
        const int we = ((j + 1) * w_roi + OUT_W - 1) / OUT_W + off;

        float m = -INFINITY;
        for (int hh = hs; hh < he; ++hh) {
            const float* row = &lds[wv][hh][0];
            for (int ww = ws; ww < we; ++ww)
                m = fmaxf(m, row[ww]);
        }
        out[(size_t)task * (OUT_H * OUT_W) + lane] = m;
    }
}

extern "C" void kernel_launch(void* const* d_in, const int* in_sizes, int n_in,
                              void* d_out, int out_size, void* d_ws, size_t ws_size,
                              hipStream_t stream) {
    const float* fm   = (const float*)d_in[0];
    const int*   rois = (const int*)d_in[1];
    float*       out  = (float*)d_out;

    const int N = in_sizes[1] / 5;            // 256 rois
    dim3 grid((N * NCH) / WPB);               // 16384 blocks
    dim3 block(256);
    roipool_kernel<<<grid, block, 0, stream>>>(fm, rois, out);
}